// Round 13
// baseline (608.245 us; speedup 1.0000x reference)
//
#include <hip/hip_runtime.h>

#define N_NODES 100000
#define N_EDGES 1600000
#define NBLK_SCAN 391  // ceil(N_NODES/256)
#define SLICE_NODES 12500   // N_NODES/8
#define BCAP 100000         // per (group,slice) bucket capacity
#define EPB 2048            // edges per bucket block
#define NBLK_BKT 782        // ceil(N_EDGES/EPB)

typedef unsigned int uint;
typedef unsigned short ushort;
typedef __attribute__((ext_vector_type(8))) short bf16x8;
typedef __attribute__((ext_vector_type(4))) float f32x4;

__device__ inline float bflo(uint u) { union { uint i; float f; } c; c.i = u << 16; return c.f; }
__device__ inline float bfhi(uint u) { union { uint i; float f; } c; c.i = u & 0xffff0000u; return c.f; }
__device__ inline float bf2f(ushort h) { union { uint i; float f; } c; c.i = (uint)h << 16; return c.f; }
__device__ inline ushort f2bf(float f) {
    union { float f; uint u; } c; c.f = f;
    uint r = (c.u + 0x7fffu + ((c.u >> 16) & 1u)) >> 16;
    return (ushort)r;
}

// weight table offsets (in ushorts) inside Whi/Wlo
#define W1_OFF   0        // [128][128]  [w1r | w1l] concat along k
#define W2L_OFF  16384    // [64][128]
#define W2R_OFF  24576    // [64][128]
#define WC1_OFF  32768    // [128][64]
#define W_TOTAL  40960

// ---------------- weight split prep: W ~= Whi + Wlo (bf16 each) ----------------
__global__ __launch_bounds__(256) void prep_weights(const float* __restrict__ w1r,
                                                    const float* __restrict__ w1l,
                                                    const float* __restrict__ w2l,
                                                    const float* __restrict__ w2r,
                                                    const float* __restrict__ wc1,
                                                    ushort* __restrict__ Whi,
                                                    ushort* __restrict__ Wlo) {
    int idx = blockIdx.x * 256 + threadIdx.x;
    if (idx >= W_TOTAL) return;
    float v;
    if (idx < W2L_OFF) {
        int o = idx >> 7, k = idx & 127;
        v = (k < 64) ? w1r[o * 64 + k] : w1l[o * 64 + (k - 64)];
    } else if (idx < W2R_OFF) {
        int t2 = idx - W2L_OFF; int o = t2 >> 7, k = t2 & 127;
        v = w2l[o * 128 + k];
    } else if (idx < WC1_OFF) {
        int t2 = idx - W2R_OFF; int o = t2 >> 7, k = t2 & 127;
        v = w2r[o * 128 + k];
    } else {
        int t2 = idx - WC1_OFF; int o = t2 >> 6, k = t2 & 63;
        v = wc1[(o & 63) * 128 + ((o >> 6) << 6) + k];
    }
    ushort hi = f2bf(v);
    ushort lo = f2bf(v - bf2f(hi));
    Whi[idx] = hi; Wlo[idx] = lo;
}

// ---------------- f32 -> bf16 convert (x) ----------------
__global__ __launch_bounds__(256) void convert_kernel(const float* __restrict__ x,
                                                      ushort* __restrict__ xb) {
    int i = blockIdx.x * 256 + threadIdx.x;
    if (i < N_NODES * 32) {
        float2 v = ((const float2*)x)[i];
        uint o = (uint)f2bf(v.x) | ((uint)f2bf(v.y) << 16);
        ((uint*)xb)[i] = o;
    }
}

// ---------------- pass A: degree count + bucket edges into GROUP-PRIVATE buckets ----
__global__ __launch_bounds__(256) void bucket_kernel(const int* __restrict__ src,
                                                     const int* __restrict__ dst,
                                                     int* __restrict__ cnt,
                                                     int* __restrict__ bcur,
                                                     uint* __restrict__ bkt) {
    __shared__ int hist[8], hist2[8], bbase[8];
    const int t = threadIdx.x;
    const int g = blockIdx.x & 7;
    const int ebase = blockIdx.x * EPB;
    const int eend = min(ebase + EPB, N_EDGES);
    if (t < 8) { hist[t] = 0; hist2[t] = 0; }
    __syncthreads();
    for (int e = ebase + t; e < eend; e += 256) {
        int d = dst[e];
        atomicAdd(&cnt[d], 1);
        atomicAdd(&hist[d / SLICE_NODES], 1);
    }
    __syncthreads();
    if (t < 8) bbase[t] = hist[t] ? atomicAdd(&bcur[g * 8 + t], hist[t]) : 0;
    __syncthreads();
    for (int e = ebase + t; e < eend; e += 256) {
        int d = dst[e], s = src[e];
        int b = d / SLICE_NODES;
        uint pack = ((uint)(d - b * SLICE_NODES) << 17) | (uint)s;
        int mo = atomicAdd(&hist2[b], 1);
        int pos = bbase[b] + mo;
        if (pos < BCAP) bkt[(size_t)(g * 8 + b) * BCAP + pos] = pack;
    }
}

// ---------------- scan step 1 ----------------
__global__ __launch_bounds__(256) void scan_block_sums(const int* __restrict__ cnt,
                                                       int* __restrict__ partial) {
    __shared__ int red[4];
    int i = blockIdx.x * 256 + threadIdx.x;
    int v = (i < N_NODES) ? cnt[i] : 0;
#pragma unroll
    for (int off = 32; off; off >>= 1) v += __shfl_down(v, off, 64);
    if ((threadIdx.x & 63) == 0) red[threadIdx.x >> 6] = v;
    __syncthreads();
    if (threadIdx.x == 0) partial[blockIdx.x] = red[0] + red[1] + red[2] + red[3];
}

// ---------------- scan step 2 ----------------
__global__ __launch_bounds__(512) void scan_top(int* __restrict__ partial) {
    __shared__ int s[512];
    int t = threadIdx.x;
    int orig = (t < NBLK_SCAN) ? partial[t] : 0;
    s[t] = orig;
    __syncthreads();
#pragma unroll
    for (int off = 1; off < 512; off <<= 1) {
        int v = (t >= off) ? s[t - off] : 0;
        __syncthreads();
        s[t] += v;
        __syncthreads();
    }
    if (t < NBLK_SCAN) partial[t] = s[t] - orig;
}

// ---------------- scan step 3 ----------------
__global__ __launch_bounds__(256) void scan_final(const int* __restrict__ cnt,
                                                  const int* __restrict__ partial,
                                                  int* __restrict__ row_start,
                                                  int* __restrict__ cursor) {
    __shared__ int s[256];
    int i = blockIdx.x * 256 + threadIdx.x;
    int t = threadIdx.x;
    int orig = (i < N_NODES) ? cnt[i] : 0;
    s[t] = orig;
    __syncthreads();
#pragma unroll
    for (int off = 1; off < 256; off <<= 1) {
        int v = (t >= off) ? s[t - off] : 0;
        __syncthreads();
        s[t] += v;
        __syncthreads();
    }
    if (i < N_NODES) {
        int rs = partial[blockIdx.x] + s[t] - orig;
        row_start[i] = rs;
        cursor[i] = rs;
    }
}

// ---------------- pass B: fill nbr from (g,s) buckets (XCD-local writes) -------------
__global__ __launch_bounds__(256) void fill_bucketed(const uint* __restrict__ bkt,
                                                     const int* __restrict__ bcur,
                                                     int* __restrict__ cursor,
                                                     int* __restrict__ nbr) {
    int s = blockIdx.x & 7;
    int g = (blockIdx.x >> 3) & 7;
    int chunk = blockIdx.x >> 6;   // 0..15
    int count = min(bcur[g * 8 + s], BCAP);
    int per = (count + 15) >> 4;
    int start = chunk * per;
    int end = min(start + per, count);
    const uint* B = bkt + (size_t)(g * 8 + s) * BCAP;
    for (int i = start + threadIdx.x; i < end; i += 256) {
        uint p = B[i];
        int d = s * SLICE_NODES + (int)(p >> 17);
        int pos = atomicAdd(&cursor[d], 1);
        nbr[pos] = (int)(p & 0x1FFFFu);
    }
}

// ---------------- gather-mean, bf16 features, D=64, 8-deep MLP, bf16 output ----------
__global__ __launch_bounds__(256) void agg_mean64_bf16(const int* __restrict__ row_start,
                                                       const int* __restrict__ cnt,
                                                       const int* __restrict__ nbr,
                                                       const ushort* __restrict__ feat,
                                                       ushort* __restrict__ meanb) {
    int node = blockIdx.x * 4 + (threadIdx.x >> 6);
    if (node >= N_NODES) return;
    int lane = threadIdx.x & 63;
    int half = lane >> 5;
    int f2   = lane & 31;
    int s = row_start[node];
    int d = cnt[node];
    float ax = 0.0f, ay = 0.0f;
    int p = 0;
    for (; p + 8 <= d; p += 8) {
        int n0 = nbr[s + p + half];
        int n1 = nbr[s + p + 2 + half];
        int n2 = nbr[s + p + 4 + half];
        int n3 = nbr[s + p + 6 + half];
        uint w0 = *(const uint*)(feat + (size_t)n0 * 64 + f2 * 2);
        uint w1 = *(const uint*)(feat + (size_t)n1 * 64 + f2 * 2);
        uint w2 = *(const uint*)(feat + (size_t)n2 * 64 + f2 * 2);
        uint w3 = *(const uint*)(feat + (size_t)n3 * 64 + f2 * 2);
        ax += bflo(w0) + bflo(w1) + bflo(w2) + bflo(w3);
        ay += bfhi(w0) + bfhi(w1) + bfhi(w2) + bfhi(w3);
    }
    for (; p + 2 <= d; p += 2) {
        int n0 = nbr[s + p + half];
        uint w0 = *(const uint*)(feat + (size_t)n0 * 64 + f2 * 2);
        ax += bflo(w0);
        ay += bfhi(w0);
    }
    if (p < d && half == 0) {
        int n0 = nbr[s + p];
        uint w0 = *(const uint*)(feat + (size_t)n0 * 64 + f2 * 2);
        ax += bflo(w0);
        ay += bfhi(w0);
    }
    ax += __shfl_xor(ax, 32, 64);
    ay += __shfl_xor(ay, 32, 64);
    if (half == 0) {
        float inv = 1.0f / fmaxf((float)d, 1.0f);
        uint o = (uint)f2bf(ax * inv) | ((uint)f2bf(ay * inv) << 16);
        ((uint*)meanb)[(size_t)node * 32 + f2] = o;
    }
}

// ======== MFMA transform kernels (bf16 hi/lo split, 3-product compensation) ========
#define MFMA __builtin_amdgcn_mfma_f32_16x16x32_bf16

// G1+G2: h1 = relu([x|mean1]@W1^T + b1l); y2 = h1@w2l^T
// mean1 input is bf16 (lo = 0); h1 stored globally hi-only; full hi/lo in LDS for G2.
__global__ __launch_bounds__(256) void g1g2_kernel(const float* __restrict__ x,
                                                   const ushort* __restrict__ mean1b,
                                                   const ushort* __restrict__ Whi,
                                                   const ushort* __restrict__ Wlo,
                                                   const float* __restrict__ b1l,
                                                   ushort* __restrict__ h1hi,
                                                   ushort* __restrict__ y2b) {
    __shared__ ushort Ah[64 * 136];
    __shared__ ushort Al[64 * 136];
    const int t = threadIdx.x;
    const int l = t & 63;
    const int wv = t >> 6;
    const int base = blockIdx.x * 64;
    const int lr = l & 15;
    const int lk = (l >> 4) * 8;

    // x half (f32 source, hi/lo split), cols 0..63
    for (int idx = t; idx < 1024; idx += 256) {
        int n = idx >> 4;
        int k0 = (idx & 15) * 4;
        int gn = base + n;
        float4 v = make_float4(0.f, 0.f, 0.f, 0.f);
        if (gn < N_NODES) v = *(const float4*)&x[(size_t)gn * 64 + k0];
        ushort h0 = f2bf(v.x), h1_ = f2bf(v.y), h2_ = f2bf(v.z), h3 = f2bf(v.w);
        ushort l0 = f2bf(v.x - bf2f(h0)), l1 = f2bf(v.y - bf2f(h1_));
        ushort l2 = f2bf(v.z - bf2f(h2_)), l3 = f2bf(v.w - bf2f(h3));
        uint2 ph; ph.x = (uint)h0 | ((uint)h1_ << 16); ph.y = (uint)h2_ | ((uint)h3 << 16);
        uint2 pl; pl.x = (uint)l0 | ((uint)l1 << 16); pl.y = (uint)l2 | ((uint)l3 << 16);
        *(uint2*)&Ah[n * 136 + k0] = ph;
        *(uint2*)&Al[n * 136 + k0] = pl;
    }
    // mean half (bf16 source, lo = 0), cols 64..127
    for (int idx = t; idx < 1024; idx += 256) {
        int n = idx >> 4;
        int c4 = (idx & 15) * 4;
        int gn = base + n;
        uint2 vh = make_uint2(0u, 0u);
        if (gn < N_NODES) vh = *(const uint2*)&mean1b[(size_t)gn * 64 + c4];
        *(uint2*)&Ah[n * 136 + 64 + c4] = vh;
        *(uint2*)&Al[n * 136 + 64 + c4] = make_uint2(0u, 0u);
    }
    __syncthreads();

    f32x4 acc[4][2];
#pragma unroll
    for (int m4 = 0; m4 < 4; ++m4)
#pragma unroll
        for (int n2 = 0; n2 < 2; ++n2) acc[m4][n2] = (f32x4){0.f, 0.f, 0.f, 0.f};

#pragma unroll
    for (int ks = 0; ks < 4; ++ks) {
        bf16x8 ah[4], al[4];
        int aoff = lr * 136 + ks * 32 + lk;
#pragma unroll
        for (int m4 = 0; m4 < 4; ++m4) {
            ah[m4] = *(const bf16x8*)&Ah[m4 * 2176 + aoff];
            al[m4] = *(const bf16x8*)&Al[m4 * 2176 + aoff];
        }
#pragma unroll
        for (int n2 = 0; n2 < 2; ++n2) {
            int o = wv * 32 + n2 * 16 + lr;
            int woff = W1_OFF + o * 128 + ks * 32 + lk;
            bf16x8 bh = *(const bf16x8*)&Whi[woff];
            bf16x8 bl = *(const bf16x8*)&Wlo[woff];
#pragma unroll
            for (int m4 = 0; m4 < 4; ++m4) {
                acc[m4][n2] = MFMA(al[m4], bh, acc[m4][n2], 0, 0, 0);
                acc[m4][n2] = MFMA(ah[m4], bl, acc[m4][n2], 0, 0, 0);
                acc[m4][n2] = MFMA(ah[m4], bh, acc[m4][n2], 0, 0, 0);
            }
        }
    }
    __syncthreads();
    ushort* H1h = Ah;
    ushort* H1l = Al;

#pragma unroll
    for (int n2 = 0; n2 < 2; ++n2) {
        int o = wv * 32 + n2 * 16 + lr;
        float bb = b1l[o];
#pragma unroll
        for (int m4 = 0; m4 < 4; ++m4) {
#pragma unroll
            for (int r = 0; r < 4; ++r) {
                int nl = m4 * 16 + (l >> 4) * 4 + r;
                float val = fmaxf(acc[m4][n2][r] + bb, 0.f);
                ushort hi = f2bf(val);
                ushort lo = f2bf(val - bf2f(hi));
                H1h[nl * 136 + o] = hi;
                H1l[nl * 136 + o] = lo;
            }
        }
    }
    __syncthreads();

    // coalesced h1 -> global (hi only)
    for (int idx = t; idx < 2048; idx += 256) {
        int n = idx >> 5;
        int c4 = (idx & 31) * 4;
        int gn = base + n;
        if (gn < N_NODES)
            *(uint2*)&h1hi[(size_t)gn * 128 + c4] = *(uint2*)&H1h[n * 136 + c4];
    }

    // G2: y2 = h1 @ w2l^T  (full hi/lo from LDS)
    f32x4 acc2[4];
#pragma unroll
    for (int m4 = 0; m4 < 4; ++m4) acc2[m4] = (f32x4){0.f, 0.f, 0.f, 0.f};
#pragma unroll
    for (int ks = 0; ks < 4; ++ks) {
        int aoff = lr * 136 + ks * 32 + lk;
        int o2 = wv * 16 + lr;
        int woff = W2L_OFF + o2 * 128 + ks * 32 + lk;
        bf16x8 bh = *(const bf16x8*)&Whi[woff];
        bf16x8 bl = *(const bf16x8*)&Wlo[woff];
#pragma unroll
        for (int m4 = 0; m4 < 4; ++m4) {
            bf16x8 ah = *(const bf16x8*)&H1h[m4 * 2176 + aoff];
            bf16x8 al = *(const bf16x8*)&H1l[m4 * 2176 + aoff];
            acc2[m4] = MFMA(al, bh, acc2[m4], 0, 0, 0);
            acc2[m4] = MFMA(ah, bl, acc2[m4], 0, 0, 0);
            acc2[m4] = MFMA(ah, bh, acc2[m4], 0, 0, 0);
        }
    }
#pragma unroll
    for (int m4 = 0; m4 < 4; ++m4) {
#pragma unroll
        for (int r = 0; r < 4; ++r) {
            int nl = m4 * 16 + (l >> 4) * 4 + r;
            int gn = base + nl;
            if (gn < N_NODES) y2b[(size_t)gn * 64 + wv * 16 + lr] = f2bf(acc2[m4][r]);
        }
    }
}

// G3+G4: h2 = relu(h1@w2r^T + mean2 + b2l); uv = h2@wc1'^T + [bc1|0]
__global__ __launch_bounds__(256) void g3g4_kernel(const ushort* __restrict__ h1hi,
                                                   const ushort* __restrict__ mean2b,
                                                   const ushort* __restrict__ Whi,
                                                   const ushort* __restrict__ Wlo,
                                                   const float* __restrict__ b2l,
                                                   const float* __restrict__ bc1,
                                                   ushort* __restrict__ uvb) {
    __shared__ ushort H1h[64 * 136];   // reused as H2h (stride 72) after G3
    __shared__ float  M2[64 * 68];
    __shared__ ushort H2l[64 * 72];
    const int t = threadIdx.x;
    const int l = t & 63;
    const int wv = t >> 6;
    const int base = blockIdx.x * 64;
    const int lr = l & 15;
    const int lk = (l >> 4) * 8;

    for (int idx = t; idx < 2048; idx += 256) {
        int n = idx >> 5;
        int c4 = (idx & 31) * 4;
        int gn = base + n;
        uint2 vh = make_uint2(0u, 0u);
        if (gn < N_NODES) vh = *(const uint2*)&h1hi[(size_t)gn * 128 + c4];
        *(uint2*)&H1h[n * 136 + c4] = vh;
    }
    // mean2 (bf16) -> f32 LDS
    for (int idx = t; idx < 1024; idx += 256) {
        int n = idx >> 4;
        int c4 = (idx & 15) * 4;
        int gn = base + n;
        uint2 vh = make_uint2(0u, 0u);
        if (gn < N_NODES) vh = *(const uint2*)&mean2b[(size_t)gn * 64 + c4];
        float4 mv;
        mv.x = bflo(vh.x); mv.y = bfhi(vh.x); mv.z = bflo(vh.y); mv.w = bfhi(vh.y);
        *(float4*)&M2[n * 68 + c4] = mv;
    }
    __syncthreads();

    // G3 MFMA (A = h1 hi only -> 2-product chain)
    f32x4 acc[4];
#pragma unroll
    for (int m4 = 0; m4 < 4; ++m4) acc[m4] = (f32x4){0.f, 0.f, 0.f, 0.f};
#pragma unroll
    for (int ks = 0; ks < 4; ++ks) {
        int aoff = lr * 136 + ks * 32 + lk;
        int o2 = wv * 16 + lr;
        int woff = W2R_OFF + o2 * 128 + ks * 32 + lk;
        bf16x8 bh = *(const bf16x8*)&Whi[woff];
        bf16x8 bl = *(const bf16x8*)&Wlo[woff];
#pragma unroll
        for (int m4 = 0; m4 < 4; ++m4) {
            bf16x8 ah = *(const bf16x8*)&H1h[m4 * 2176 + aoff];
            acc[m4] = MFMA(ah, bl, acc[m4], 0, 0, 0);
            acc[m4] = MFMA(ah, bh, acc[m4], 0, 0, 0);
        }
    }
    __syncthreads();
    ushort* H2h = H1h;

    {
        int o2 = wv * 16 + lr;
        float bb = b2l[o2];
#pragma unroll
        for (int m4 = 0; m4 < 4; ++m4) {
#pragma unroll
            for (int r = 0; r < 4; ++r) {
                int nl = m4 * 16 + (l >> 4) * 4 + r;
                float val = fmaxf(acc[m4][r] + M2[nl * 68 + o2] + bb, 0.f);
                ushort hi = f2bf(val);
                ushort lo = f2bf(val - bf2f(hi));
                H2h[nl * 72 + o2] = hi;
                H2l[nl * 72 + o2] = lo;
            }
        }
    }
    __syncthreads();

    // G4: uv = h2 @ wc1'^T  (K=64, N=128)
    f32x4 acc4[4][2];
#pragma unroll
    for (int m4 = 0; m4 < 4; ++m4)
#pragma unroll
        for (int n2 = 0; n2 < 2; ++n2) acc4[m4][n2] = (f32x4){0.f, 0.f, 0.f, 0.f};
#pragma unroll
    for (int ks = 0; ks < 2; ++ks) {
        bf16x8 ah[4], al[4];
        int aoff = lr * 72 + ks * 32 + lk;
#pragma unroll
        for (int m4 = 0; m4 < 4; ++m4) {
            ah[m4] = *(const bf16x8*)&H2h[m4 * 1152 + aoff];
            al[m4] = *(const bf16x8*)&H2l[m4 * 1152 + aoff];
        }
#pragma unroll
        for (int n2 = 0; n2 < 2; ++n2) {
            int o = wv * 32 + n2 * 16 + lr;
            int woff = WC1_OFF + o * 64 + ks * 32 + lk;
            bf16x8 bh = *(const bf16x8*)&Whi[woff];
            bf16x8 bl = *(const bf16x8*)&Wlo[woff];
#pragma unroll
            for (int m4 = 0; m4 < 4; ++m4) {
                acc4[m4][n2] = MFMA(al[m4], bh, acc4[m4][n2], 0, 0, 0);
                acc4[m4][n2] = MFMA(ah[m4], bl, acc4[m4][n2], 0, 0, 0);
                acc4[m4][n2] = MFMA(ah[m4], bh, acc4[m4][n2], 0, 0, 0);
            }
        }
    }
#pragma unroll
    for (int n2 = 0; n2 < 2; ++n2) {
        int o = wv * 32 + n2 * 16 + lr;
        float bb = (o < 64) ? bc1[o] : 0.0f;
#pragma unroll
        for (int m4 = 0; m4 < 4; ++m4) {
#pragma unroll
            for (int r = 0; r < 4; ++r) {
                int nl = m4 * 16 + (l >> 4) * 4 + r;
                int gn = base + nl;
                if (gn < N_NODES) uvb[(size_t)gn * 128 + o] = f2bf(acc4[m4][n2][r] + bb);
            }
        }
    }
}

// ---------------- edge kernel: 2 edges/thread, 32 gathers in flight, float4 store ----
__global__ __launch_bounds__(256) void edge_kernel(const int* __restrict__ src,
                                                   const int* __restrict__ dst,
                                                   const ushort* __restrict__ uvb,
                                                   const float* __restrict__ wc2,
                                                   const float* __restrict__ bc2,
                                                   float* __restrict__ out) {
    int e0 = (blockIdx.x * 256 + threadIdx.x) * 2;
    if (e0 >= N_EDGES) return;
    const uint4* ua0 = (const uint4*)(uvb + (size_t)src[e0] * 128);
    const uint4* va0 = (const uint4*)(uvb + (size_t)dst[e0] * 128 + 64);
    const uint4* ua1 = (const uint4*)(uvb + (size_t)src[e0 + 1] * 128);
    const uint4* va1 = (const uint4*)(uvb + (size_t)dst[e0 + 1] * 128 + 64);
    float o00 = 0.f, o01 = 0.f, o10 = 0.f, o11 = 0.f;
#pragma unroll
    for (int k = 0; k < 8; ++k) {
        uint4 a0 = ua0[k], b0 = va0[k], a1 = ua1[k], b1 = va1[k];
        int i0 = k * 8;
        float h0, h1v;
#define ACCP(aw, bw, off, oA, oB)                                               \
        h0  = fmaxf(bflo(aw) + bflo(bw), 0.f);                                  \
        h1v = fmaxf(bfhi(aw) + bfhi(bw), 0.f);                                  \
        oA += wc2[i0 + off] * h0 + wc2[i0 + off + 1] * h1v;                     \
        oB += wc2[64 + i0 + off] * h0 + wc2[65 + i0 + off] * h1v;
        ACCP(a0.x, b0.x, 0, o00, o01)
        ACCP(a0.y, b0.y, 2, o00, o01)
        ACCP(a0.z, b0.z, 4, o00, o01)
        ACCP(a0.w, b0.w, 6, o00, o01)
        ACCP(a1.x, b1.x, 0, o10, o11)
        ACCP(a1.y, b1.y, 2, o10, o11)
        ACCP(a1.z, b1.z, 4, o10, o11)
        ACCP(a1.w, b1.w, 6, o10, o11)
#undef ACCP
    }
    float4 r;
    r.x = o00 + bc2[0];
    r.y = o01 + bc2[1];
    r.z = o10 + bc2[0];
    r.w = o11 + bc2[1];
    *(float4*)(out + (size_t)e0 * 2) = r;
}

extern "C" void kernel_launch(void* const* d_in, const int* in_sizes, int n_in,
                              void* d_out, int out_size, void* d_ws, size_t ws_size,
                              hipStream_t stream) {
    const float* x   = (const float*)d_in[0];
    const int*   ei  = (const int*)d_in[1];
    const float* w1l = (const float*)d_in[2];
    const float* b1l = (const float*)d_in[3];
    const float* w1r = (const float*)d_in[4];
    const float* w2l = (const float*)d_in[5];
    const float* b2l = (const float*)d_in[6];
    const float* w2r = (const float*)d_in[7];
    const float* wc1 = (const float*)d_in[8];
    const float* bc1 = (const float*)d_in[9];
    const float* wc2 = (const float*)d_in[10];
    const float* bc2 = (const float*)d_in[11];
    float* out = (float*)d_out;

    const int* srcp = ei;
    const int* dstp = ei + N_EDGES;

    // workspace layout (f32 slots)
    float*  ws     = (float*)d_ws;
    ushort* xb     = (ushort*)ws;                 // [0, 3.2M)    bf16 x (alias y2b)
    ushort* y2b    = (ushort*)ws;
    ushort* mean1b = (ushort*)(ws + 3200000);     // [3.2M, 6.4M) bf16 means (alias uvb)
    ushort* uvb    = (ushort*)(ws + 3200000);     // [3.2M, 9.6M)
    ushort* h1hi   = (ushort*)(ws + 9600000);     // [9.6M, 16M)  bf16 12.8M
    uint*   bkt    = (uint*)(ws + 16000000);      // [16M, 22.4M) 64 x BCAP uints
    ushort* mean2b = (ushort*)(ws + 22400000);    // [22.4M, 25.6M) bf16
    int*    ib     = (int*)(ws + 28800000);
    int* cnt       = ib;                 // 100000
    int* row_start = ib + 100000;        // 100000
    int* cursor    = ib + 200000;        // 100000
    int* partial   = ib + 300000;        // 512
    int* bcur      = ib + 300512;        // 64
    int* nbr       = ib + 300576;        // 1600000
    ushort* Whi = (ushort*)(ws + 30800000);
    ushort* Wlo = (ushort*)(ws + 30900000);

    hipMemsetAsync(cnt, 0, (size_t)N_NODES * 4, stream);
    hipMemsetAsync(bcur, 0, 64 * 4, stream);

    prep_weights<<<(W_TOTAL + 255) / 256, 256, 0, stream>>>(w1r, w1l, w2l, w2r, wc1, Whi, Wlo);
    convert_kernel<<<12500, 256, 0, stream>>>(x, xb);

    bucket_kernel<<<NBLK_BKT, 256, 0, stream>>>(srcp, dstp, cnt, bcur, bkt);
    scan_block_sums<<<NBLK_SCAN, 256, 0, stream>>>(cnt, partial);
    scan_top<<<1, 512, 0, stream>>>(partial);
    scan_final<<<NBLK_SCAN, 256, 0, stream>>>(cnt, partial, row_start, cursor);
    fill_bucketed<<<1024, 256, 0, stream>>>(bkt, bcur, cursor, nbr);

    const int NAB = (N_NODES + 3) / 4;
    const int NB  = (N_NODES + 63) / 64;

    agg_mean64_bf16<<<NAB, 256, 0, stream>>>(row_start, cnt, nbr, xb, mean1b);
    g1g2_kernel<<<NB, 256, 0, stream>>>(x, mean1b, Whi, Wlo, b1l, h1hi, y2b);
    agg_mean64_bf16<<<NAB, 256, 0, stream>>>(row_start, cnt, nbr, y2b, mean2b);
    g3g4_kernel<<<NB, 256, 0, stream>>>(h1hi, mean2b, Whi, Wlo, b2l, bc1, uvb);
    edge_kernel<<<(N_EDGES / 2 + 255) / 256, 256, 0, stream>>>(srcp, dstp, uvb, wc2, bc2, out);
}

// Round 14
// 427.648 us; speedup vs baseline: 1.4223x; 1.4223x over previous
//
#include <hip/hip_runtime.h>

#define N_NODES 100000
#define N_EDGES 1600000
#define NBLK_SCAN 391  // ceil(N_NODES/256)
#define SLICE_NODES 12500   // N_NODES/8
#define BCAP 100000         // per (group,slice) bucket capacity
#define EPB 2048            // edges per bucket block
#define NBLK_BKT 782        // ceil(N_EDGES/EPB)

typedef unsigned int uint;
typedef unsigned short ushort;
typedef __attribute__((ext_vector_type(8))) short bf16x8;
typedef __attribute__((ext_vector_type(4))) float f32x4;

__device__ inline float bflo(uint u) { union { uint i; float f; } c; c.i = u << 16; return c.f; }
__device__ inline float bfhi(uint u) { union { uint i; float f; } c; c.i = u & 0xffff0000u; return c.f; }
__device__ inline float bf2f(ushort h) { union { uint i; float f; } c; c.i = (uint)h << 16; return c.f; }
__device__ inline ushort f2bf(float f) {
    union { float f; uint u; } c; c.f = f;
    uint r = (c.u + 0x7fffu + ((c.u >> 16) & 1u)) >> 16;
    return (ushort)r;
}

// weight table offsets (in ushorts) inside Whi/Wlo
#define W1_OFF   0        // [128][128]  [w1r | w1l] concat along k
#define W2L_OFF  16384    // [64][128]
#define W2R_OFF  24576    // [64][128]
#define WC1_OFF  32768    // [128][64]
#define W_TOTAL  40960

// ---------------- weight split prep: W ~= Whi + Wlo (bf16 each) ----------------
__global__ __launch_bounds__(256) void prep_weights(const float* __restrict__ w1r,
                                                    const float* __restrict__ w1l,
                                                    const float* __restrict__ w2l,
                                                    const float* __restrict__ w2r,
                                                    const float* __restrict__ wc1,
                                                    ushort* __restrict__ Whi,
                                                    ushort* __restrict__ Wlo) {
    int idx = blockIdx.x * 256 + threadIdx.x;
    if (idx >= W_TOTAL) return;
    float v;
    if (idx < W2L_OFF) {
        int o = idx >> 7, k = idx & 127;
        v = (k < 64) ? w1r[o * 64 + k] : w1l[o * 64 + (k - 64)];
    } else if (idx < W2R_OFF) {
        int t2 = idx - W2L_OFF; int o = t2 >> 7, k = t2 & 127;
        v = w2l[o * 128 + k];
    } else if (idx < WC1_OFF) {
        int t2 = idx - W2R_OFF; int o = t2 >> 7, k = t2 & 127;
        v = w2r[o * 128 + k];
    } else {
        int t2 = idx - WC1_OFF; int o = t2 >> 6, k = t2 & 63;
        v = wc1[(o & 63) * 128 + ((o >> 6) << 6) + k];
    }
    ushort hi = f2bf(v);
    ushort lo = f2bf(v - bf2f(hi));
    Whi[idx] = hi; Wlo[idx] = lo;
}

// ---------------- f32 -> bf16 convert (x) ----------------
__global__ __launch_bounds__(256) void convert_kernel(const float* __restrict__ x,
                                                      ushort* __restrict__ xb) {
    int i = blockIdx.x * 256 + threadIdx.x;
    if (i < N_NODES * 32) {
        float2 v = ((const float2*)x)[i];
        uint o = (uint)f2bf(v.x) | ((uint)f2bf(v.y) << 16);
        ((uint*)xb)[i] = o;
    }
}

// ---------------- pass A: degree count + bucket edges into GROUP-PRIVATE buckets ----
__global__ __launch_bounds__(256) void bucket_kernel(const int* __restrict__ src,
                                                     const int* __restrict__ dst,
                                                     int* __restrict__ cnt,
                                                     int* __restrict__ bcur,
                                                     uint* __restrict__ bkt) {
    __shared__ int hist[8], hist2[8], bbase[8];
    const int t = threadIdx.x;
    const int g = blockIdx.x & 7;
    const int ebase = blockIdx.x * EPB;
    const int eend = min(ebase + EPB, N_EDGES);
    if (t < 8) { hist[t] = 0; hist2[t] = 0; }
    __syncthreads();
    for (int e = ebase + t; e < eend; e += 256) {
        int d = dst[e];
        atomicAdd(&cnt[d], 1);
        atomicAdd(&hist[d / SLICE_NODES], 1);
    }
    __syncthreads();
    if (t < 8) bbase[t] = hist[t] ? atomicAdd(&bcur[g * 8 + t], hist[t]) : 0;
    __syncthreads();
    for (int e = ebase + t; e < eend; e += 256) {
        int d = dst[e], s = src[e];
        int b = d / SLICE_NODES;
        uint pack = ((uint)(d - b * SLICE_NODES) << 17) | (uint)s;
        int mo = atomicAdd(&hist2[b], 1);
        int pos = bbase[b] + mo;
        if (pos < BCAP) bkt[(size_t)(g * 8 + b) * BCAP + pos] = pack;
    }
}

// ---------------- scan step 1 ----------------
__global__ __launch_bounds__(256) void scan_block_sums(const int* __restrict__ cnt,
                                                       int* __restrict__ partial) {
    __shared__ int red[4];
    int i = blockIdx.x * 256 + threadIdx.x;
    int v = (i < N_NODES) ? cnt[i] : 0;
#pragma unroll
    for (int off = 32; off; off >>= 1) v += __shfl_down(v, off, 64);
    if ((threadIdx.x & 63) == 0) red[threadIdx.x >> 6] = v;
    __syncthreads();
    if (threadIdx.x == 0) partial[blockIdx.x] = red[0] + red[1] + red[2] + red[3];
}

// ---------------- scan step 2 ----------------
__global__ __launch_bounds__(512) void scan_top(int* __restrict__ partial) {
    __shared__ int s[512];
    int t = threadIdx.x;
    int orig = (t < NBLK_SCAN) ? partial[t] : 0;
    s[t] = orig;
    __syncthreads();
#pragma unroll
    for (int off = 1; off < 512; off <<= 1) {
        int v = (t >= off) ? s[t - off] : 0;
        __syncthreads();
        s[t] += v;
        __syncthreads();
    }
    if (t < NBLK_SCAN) partial[t] = s[t] - orig;
}

// ---------------- scan step 3 ----------------
__global__ __launch_bounds__(256) void scan_final(const int* __restrict__ cnt,
                                                  const int* __restrict__ partial,
                                                  int* __restrict__ row_start,
                                                  int* __restrict__ cursor) {
    __shared__ int s[256];
    int i = blockIdx.x * 256 + threadIdx.x;
    int t = threadIdx.x;
    int orig = (i < N_NODES) ? cnt[i] : 0;
    s[t] = orig;
    __syncthreads();
#pragma unroll
    for (int off = 1; off < 256; off <<= 1) {
        int v = (t >= off) ? s[t - off] : 0;
        __syncthreads();
        s[t] += v;
        __syncthreads();
    }
    if (i < N_NODES) {
        int rs = partial[blockIdx.x] + s[t] - orig;
        row_start[i] = rs;
        cursor[i] = rs;
    }
}

// ---------------- pass B: fill nbr from (g,s) buckets (XCD-local writes) -------------
__global__ __launch_bounds__(256) void fill_bucketed(const uint* __restrict__ bkt,
                                                     const int* __restrict__ bcur,
                                                     int* __restrict__ cursor,
                                                     int* __restrict__ nbr) {
    int s = blockIdx.x & 7;
    int g = (blockIdx.x >> 3) & 7;
    int chunk = blockIdx.x >> 6;   // 0..15
    int count = min(bcur[g * 8 + s], BCAP);
    int per = (count + 15) >> 4;
    int start = chunk * per;
    int end = min(start + per, count);
    const uint* B = bkt + (size_t)(g * 8 + s) * BCAP;
    for (int i = start + threadIdx.x; i < end; i += 256) {
        uint p = B[i];
        int d = s * SLICE_NODES + (int)(p >> 17);
        int pos = atomicAdd(&cursor[d], 1);
        nbr[pos] = (int)(p & 0x1FFFFu);
    }
}

// ---------------- gather-mean, bf16 features, D=64, 8-deep MLP, bf16 output ----------
__global__ __launch_bounds__(256) void agg_mean64_bf16(const int* __restrict__ row_start,
                                                       const int* __restrict__ cnt,
                                                       const int* __restrict__ nbr,
                                                       const ushort* __restrict__ feat,
                                                       ushort* __restrict__ meanb) {
    int node = blockIdx.x * 4 + (threadIdx.x >> 6);
    if (node >= N_NODES) return;
    int lane = threadIdx.x & 63;
    int half = lane >> 5;
    int f2   = lane & 31;
    int s = row_start[node];
    int d = cnt[node];
    float ax = 0.0f, ay = 0.0f;
    int p = 0;
    for (; p + 8 <= d; p += 8) {
        int n0 = nbr[s + p + half];
        int n1 = nbr[s + p + 2 + half];
        int n2 = nbr[s + p + 4 + half];
        int n3 = nbr[s + p + 6 + half];
        uint w0 = *(const uint*)(feat + (size_t)n0 * 64 + f2 * 2);
        uint w1 = *(const uint*)(feat + (size_t)n1 * 64 + f2 * 2);
        uint w2 = *(const uint*)(feat + (size_t)n2 * 64 + f2 * 2);
        uint w3 = *(const uint*)(feat + (size_t)n3 * 64 + f2 * 2);
        ax += bflo(w0) + bflo(w1) + bflo(w2) + bflo(w3);
        ay += bfhi(w0) + bfhi(w1) + bfhi(w2) + bfhi(w3);
    }
    for (; p + 2 <= d; p += 2) {
        int n0 = nbr[s + p + half];
        uint w0 = *(const uint*)(feat + (size_t)n0 * 64 + f2 * 2);
        ax += bflo(w0);
        ay += bfhi(w0);
    }
    if (p < d && half == 0) {
        int n0 = nbr[s + p];
        uint w0 = *(const uint*)(feat + (size_t)n0 * 64 + f2 * 2);
        ax += bflo(w0);
        ay += bfhi(w0);
    }
    ax += __shfl_xor(ax, 32, 64);
    ay += __shfl_xor(ay, 32, 64);
    if (half == 0) {
        float inv = 1.0f / fmaxf((float)d, 1.0f);
        uint o = (uint)f2bf(ax * inv) | ((uint)f2bf(ay * inv) << 16);
        ((uint*)meanb)[(size_t)node * 32 + f2] = o;
    }
}

// ======== MFMA transform kernels (bf16 hi/lo split, 3-product compensation) ========
#define MFMA __builtin_amdgcn_mfma_f32_16x16x32_bf16

// G1+G2: h1 = relu([x|mean1]@W1^T + b1l); y2 = h1@w2l^T
// mean1 input is bf16 (lo = 0); h1 stored globally hi-only; full hi/lo in LDS for G2.
__global__ __launch_bounds__(256) void g1g2_kernel(const float* __restrict__ x,
                                                   const ushort* __restrict__ mean1b,
                                                   const ushort* __restrict__ Whi,
                                                   const ushort* __restrict__ Wlo,
                                                   const float* __restrict__ b1l,
                                                   ushort* __restrict__ h1hi,
                                                   ushort* __restrict__ y2b) {
    __shared__ ushort Ah[64 * 136];
    __shared__ ushort Al[64 * 136];
    const int t = threadIdx.x;
    const int l = t & 63;
    const int wv = t >> 6;
    const int base = blockIdx.x * 64;
    const int lr = l & 15;
    const int lk = (l >> 4) * 8;

    // x half (f32 source, hi/lo split), cols 0..63
    for (int idx = t; idx < 1024; idx += 256) {
        int n = idx >> 4;
        int k0 = (idx & 15) * 4;
        int gn = base + n;
        float4 v = make_float4(0.f, 0.f, 0.f, 0.f);
        if (gn < N_NODES) v = *(const float4*)&x[(size_t)gn * 64 + k0];
        ushort h0 = f2bf(v.x), h1_ = f2bf(v.y), h2_ = f2bf(v.z), h3 = f2bf(v.w);
        ushort l0 = f2bf(v.x - bf2f(h0)), l1 = f2bf(v.y - bf2f(h1_));
        ushort l2 = f2bf(v.z - bf2f(h2_)), l3 = f2bf(v.w - bf2f(h3));
        uint2 ph; ph.x = (uint)h0 | ((uint)h1_ << 16); ph.y = (uint)h2_ | ((uint)h3 << 16);
        uint2 pl; pl.x = (uint)l0 | ((uint)l1 << 16); pl.y = (uint)l2 | ((uint)l3 << 16);
        *(uint2*)&Ah[n * 136 + k0] = ph;
        *(uint2*)&Al[n * 136 + k0] = pl;
    }
    // mean half (bf16 source, lo = 0), cols 64..127
    for (int idx = t; idx < 1024; idx += 256) {
        int n = idx >> 4;
        int c4 = (idx & 15) * 4;
        int gn = base + n;
        uint2 vh = make_uint2(0u, 0u);
        if (gn < N_NODES) vh = *(const uint2*)&mean1b[(size_t)gn * 64 + c4];
        *(uint2*)&Ah[n * 136 + 64 + c4] = vh;
        *(uint2*)&Al[n * 136 + 64 + c4] = make_uint2(0u, 0u);
    }
    __syncthreads();

    f32x4 acc[4][2];
#pragma unroll
    for (int m4 = 0; m4 < 4; ++m4)
#pragma unroll
        for (int n2 = 0; n2 < 2; ++n2) acc[m4][n2] = (f32x4){0.f, 0.f, 0.f, 0.f};

#pragma unroll
    for (int ks = 0; ks < 4; ++ks) {
        bf16x8 ah[4], al[4];
        int aoff = lr * 136 + ks * 32 + lk;
#pragma unroll
        for (int m4 = 0; m4 < 4; ++m4) {
            ah[m4] = *(const bf16x8*)&Ah[m4 * 2176 + aoff];
            al[m4] = *(const bf16x8*)&Al[m4 * 2176 + aoff];
        }
#pragma unroll
        for (int n2 = 0; n2 < 2; ++n2) {
            int o = wv * 32 + n2 * 16 + lr;
            int woff = W1_OFF + o * 128 + ks * 32 + lk;
            bf16x8 bh = *(const bf16x8*)&Whi[woff];
            bf16x8 bl = *(const bf16x8*)&Wlo[woff];
#pragma unroll
            for (int m4 = 0; m4 < 4; ++m4) {
                acc[m4][n2] = MFMA(al[m4], bh, acc[m4][n2], 0, 0, 0);
                acc[m4][n2] = MFMA(ah[m4], bl, acc[m4][n2], 0, 0, 0);
                acc[m4][n2] = MFMA(ah[m4], bh, acc[m4][n2], 0, 0, 0);
            }
        }
    }
    __syncthreads();
    ushort* H1h = Ah;
    ushort* H1l = Al;

#pragma unroll
    for (int n2 = 0; n2 < 2; ++n2) {
        int o = wv * 32 + n2 * 16 + lr;
        float bb = b1l[o];
#pragma unroll
        for (int m4 = 0; m4 < 4; ++m4) {
#pragma unroll
            for (int r = 0; r < 4; ++r) {
                int nl = m4 * 16 + (l >> 4) * 4 + r;
                float val = fmaxf(acc[m4][n2][r] + bb, 0.f);
                ushort hi = f2bf(val);
                ushort lo = f2bf(val - bf2f(hi));
                H1h[nl * 136 + o] = hi;
                H1l[nl * 136 + o] = lo;
            }
        }
    }
    __syncthreads();

    // coalesced h1 -> global (hi only)
    for (int idx = t; idx < 2048; idx += 256) {
        int n = idx >> 5;
        int c4 = (idx & 31) * 4;
        int gn = base + n;
        if (gn < N_NODES)
            *(uint2*)&h1hi[(size_t)gn * 128 + c4] = *(uint2*)&H1h[n * 136 + c4];
    }

    // G2: y2 = h1 @ w2l^T  (full hi/lo from LDS)
    f32x4 acc2[4];
#pragma unroll
    for (int m4 = 0; m4 < 4; ++m4) acc2[m4] = (f32x4){0.f, 0.f, 0.f, 0.f};
#pragma unroll
    for (int ks = 0; ks < 4; ++ks) {
        int aoff = lr * 136 + ks * 32 + lk;
        int o2 = wv * 16 + lr;
        int woff = W2L_OFF + o2 * 128 + ks * 32 + lk;
        bf16x8 bh = *(const bf16x8*)&Whi[woff];
        bf16x8 bl = *(const bf16x8*)&Wlo[woff];
#pragma unroll
        for (int m4 = 0; m4 < 4; ++m4) {
            bf16x8 ah = *(const bf16x8*)&H1h[m4 * 2176 + aoff];
            bf16x8 al = *(const bf16x8*)&H1l[m4 * 2176 + aoff];
            acc2[m4] = MFMA(al, bh, acc2[m4], 0, 0, 0);
            acc2[m4] = MFMA(ah, bl, acc2[m4], 0, 0, 0);
            acc2[m4] = MFMA(ah, bh, acc2[m4], 0, 0, 0);
        }
    }
#pragma unroll
    for (int m4 = 0; m4 < 4; ++m4) {
#pragma unroll
        for (int r = 0; r < 4; ++r) {
            int nl = m4 * 16 + (l >> 4) * 4 + r;
            int gn = base + nl;
            if (gn < N_NODES) y2b[(size_t)gn * 64 + wv * 16 + lr] = f2bf(acc2[m4][r]);
        }
    }
}

// G3+G4: h2 = relu(h1@w2r^T + mean2 + b2l); uv = h2@wc1'^T + [bc1|0]
__global__ __launch_bounds__(256) void g3g4_kernel(const ushort* __restrict__ h1hi,
                                                   const ushort* __restrict__ mean2b,
                                                   const ushort* __restrict__ Whi,
                                                   const ushort* __restrict__ Wlo,
                                                   const float* __restrict__ b2l,
                                                   const float* __restrict__ bc1,
                                                   ushort* __restrict__ uvb) {
    __shared__ ushort H1h[64 * 136];   // reused as H2h (stride 72) after G3
    __shared__ float  M2[64 * 68];
    __shared__ ushort H2l[64 * 72];
    const int t = threadIdx.x;
    const int l = t & 63;
    const int wv = t >> 6;
    const int base = blockIdx.x * 64;
    const int lr = l & 15;
    const int lk = (l >> 4) * 8;

    for (int idx = t; idx < 2048; idx += 256) {
        int n = idx >> 5;
        int c4 = (idx & 31) * 4;
        int gn = base + n;
        uint2 vh = make_uint2(0u, 0u);
        if (gn < N_NODES) vh = *(const uint2*)&h1hi[(size_t)gn * 128 + c4];
        *(uint2*)&H1h[n * 136 + c4] = vh;
    }
    // mean2 (bf16) -> f32 LDS
    for (int idx = t; idx < 1024; idx += 256) {
        int n = idx >> 4;
        int c4 = (idx & 15) * 4;
        int gn = base + n;
        uint2 vh = make_uint2(0u, 0u);
        if (gn < N_NODES) vh = *(const uint2*)&mean2b[(size_t)gn * 64 + c4];
        float4 mv;
        mv.x = bflo(vh.x); mv.y = bfhi(vh.x); mv.z = bflo(vh.y); mv.w = bfhi(vh.y);
        *(float4*)&M2[n * 68 + c4] = mv;
    }
    __syncthreads();

    // G3 MFMA (A = h1 hi only -> 2-product chain)
    f32x4 acc[4];
#pragma unroll
    for (int m4 = 0; m4 < 4; ++m4) acc[m4] = (f32x4){0.f, 0.f, 0.f, 0.f};
#pragma unroll
    for (int ks = 0; ks < 4; ++ks) {
        int aoff = lr * 136 + ks * 32 + lk;
        int o2 = wv * 16 + lr;
        int woff = W2R_OFF + o2 * 128 + ks * 32 + lk;
        bf16x8 bh = *(const bf16x8*)&Whi[woff];
        bf16x8 bl = *(const bf16x8*)&Wlo[woff];
#pragma unroll
        for (int m4 = 0; m4 < 4; ++m4) {
            bf16x8 ah = *(const bf16x8*)&H1h[m4 * 2176 + aoff];
            acc[m4] = MFMA(ah, bl, acc[m4], 0, 0, 0);
            acc[m4] = MFMA(ah, bh, acc[m4], 0, 0, 0);
        }
    }
    __syncthreads();
    ushort* H2h = H1h;

    {
        int o2 = wv * 16 + lr;
        float bb = b2l[o2];
#pragma unroll
        for (int m4 = 0; m4 < 4; ++m4) {
#pragma unroll
            for (int r = 0; r < 4; ++r) {
                int nl = m4 * 16 + (l >> 4) * 4 + r;
                float val = fmaxf(acc[m4][r] + M2[nl * 68 + o2] + bb, 0.f);
                ushort hi = f2bf(val);
                ushort lo = f2bf(val - bf2f(hi));
                H2h[nl * 72 + o2] = hi;
                H2l[nl * 72 + o2] = lo;
            }
        }
    }
    __syncthreads();

    // G4: uv = h2 @ wc1'^T  (K=64, N=128)
    f32x4 acc4[4][2];
#pragma unroll
    for (int m4 = 0; m4 < 4; ++m4)
#pragma unroll
        for (int n2 = 0; n2 < 2; ++n2) acc4[m4][n2] = (f32x4){0.f, 0.f, 0.f, 0.f};
#pragma unroll
    for (int ks = 0; ks < 2; ++ks) {
        bf16x8 ah[4], al[4];
        int aoff = lr * 72 + ks * 32 + lk;
#pragma unroll
        for (int m4 = 0; m4 < 4; ++m4) {
            ah[m4] = *(const bf16x8*)&H2h[m4 * 1152 + aoff];
            al[m4] = *(const bf16x8*)&H2l[m4 * 1152 + aoff];
        }
#pragma unroll
        for (int n2 = 0; n2 < 2; ++n2) {
            int o = wv * 32 + n2 * 16 + lr;
            int woff = WC1_OFF + o * 64 + ks * 32 + lk;
            bf16x8 bh = *(const bf16x8*)&Whi[woff];
            bf16x8 bl = *(const bf16x8*)&Wlo[woff];
#pragma unroll
            for (int m4 = 0; m4 < 4; ++m4) {
                acc4[m4][n2] = MFMA(al[m4], bh, acc4[m4][n2], 0, 0, 0);
                acc4[m4][n2] = MFMA(ah[m4], bl, acc4[m4][n2], 0, 0, 0);
                acc4[m4][n2] = MFMA(ah[m4], bh, acc4[m4][n2], 0, 0, 0);
            }
        }
    }
#pragma unroll
    for (int n2 = 0; n2 < 2; ++n2) {
        int o = wv * 32 + n2 * 16 + lr;
        float bb = (o < 64) ? bc1[o] : 0.0f;
#pragma unroll
        for (int m4 = 0; m4 < 4; ++m4) {
#pragma unroll
            for (int r = 0; r < 4; ++r) {
                int nl = m4 * 16 + (l >> 4) * 4 + r;
                int gn = base + nl;
                if (gn < N_NODES) uvb[(size_t)gn * 128 + o] = f2bf(acc4[m4][n2][r] + bb);
            }
        }
    }
}

// ---------------- edge kernel: out = wc2 @ relu(u[src]+v[dst]) + bc2, bf16 uv ---------
__global__ __launch_bounds__(256) void edge_kernel(const int* __restrict__ src,
                                                   const int* __restrict__ dst,
                                                   const ushort* __restrict__ uvb,
                                                   const float* __restrict__ wc2,
                                                   const float* __restrict__ bc2,
                                                   float* __restrict__ out) {
    int e = blockIdx.x * blockDim.x + threadIdx.x;
    if (e >= N_EDGES) return;
    const uint4* ua = (const uint4*)(uvb + (size_t)src[e] * 128);
    const uint4* va = (const uint4*)(uvb + (size_t)dst[e] * 128 + 64);
    float o0 = 0.0f, o1 = 0.0f;
#pragma unroll
    for (int k = 0; k < 8; ++k) {
        uint4 a = ua[k], b = va[k];
        int i0 = k * 8;
        float h0, h1v;
        h0 = fmaxf(bflo(a.x) + bflo(b.x), 0.f); h1v = fmaxf(bfhi(a.x) + bfhi(b.x), 0.f);
        o0 += wc2[i0] * h0 + wc2[i0 + 1] * h1v;  o1 += wc2[64 + i0] * h0 + wc2[65 + i0] * h1v;
        h0 = fmaxf(bflo(a.y) + bflo(b.y), 0.f); h1v = fmaxf(bfhi(a.y) + bfhi(b.y), 0.f);
        o0 += wc2[i0 + 2] * h0 + wc2[i0 + 3] * h1v;  o1 += wc2[66 + i0] * h0 + wc2[67 + i0] * h1v;
        h0 = fmaxf(bflo(a.z) + bflo(b.z), 0.f); h1v = fmaxf(bfhi(a.z) + bfhi(b.z), 0.f);
        o0 += wc2[i0 + 4] * h0 + wc2[i0 + 5] * h1v;  o1 += wc2[68 + i0] * h0 + wc2[69 + i0] * h1v;
        h0 = fmaxf(bflo(a.w) + bflo(b.w), 0.f); h1v = fmaxf(bfhi(a.w) + bfhi(b.w), 0.f);
        o0 += wc2[i0 + 6] * h0 + wc2[i0 + 7] * h1v;  o1 += wc2[70 + i0] * h0 + wc2[71 + i0] * h1v;
    }
    float2 r;
    r.x = o0 + bc2[0];
    r.y = o1 + bc2[1];
    *(float2*)(out + (size_t)e * 2) = r;
}

extern "C" void kernel_launch(void* const* d_in, const int* in_sizes, int n_in,
                              void* d_out, int out_size, void* d_ws, size_t ws_size,
                              hipStream_t stream) {
    const float* x   = (const float*)d_in[0];
    const int*   ei  = (const int*)d_in[1];
    const float* w1l = (const float*)d_in[2];
    const float* b1l = (const float*)d_in[3];
    const float* w1r = (const float*)d_in[4];
    const float* w2l = (const float*)d_in[5];
    const float* b2l = (const float*)d_in[6];
    const float* w2r = (const float*)d_in[7];
    const float* wc1 = (const float*)d_in[8];
    const float* bc1 = (const float*)d_in[9];
    const float* wc2 = (const float*)d_in[10];
    const float* bc2 = (const float*)d_in[11];
    float* out = (float*)d_out;

    const int* srcp = ei;
    const int* dstp = ei + N_EDGES;

    // workspace layout (f32 slots)
    float*  ws     = (float*)d_ws;
    ushort* xb     = (ushort*)ws;                 // [0, 3.2M)    bf16 x (alias y2b)
    ushort* y2b    = (ushort*)ws;
    ushort* mean1b = (ushort*)(ws + 3200000);     // [3.2M, 6.4M) bf16 means (alias uvb)
    ushort* uvb    = (ushort*)(ws + 3200000);     // [3.2M, 9.6M)
    ushort* h1hi   = (ushort*)(ws + 9600000);     // [9.6M, 16M)  bf16 12.8M
    uint*   bkt    = (uint*)(ws + 16000000);      // [16M, 22.4M) 64 x BCAP uints
    ushort* mean2b = (ushort*)(ws + 22400000);    // [22.4M, 25.6M) bf16
    int*    ib     = (int*)(ws + 28800000);
    int* cnt       = ib;                 // 100000
    int* row_start = ib + 100000;        // 100000
    int* cursor    = ib + 200000;        // 100000
    int* partial   = ib + 300000;        // 512
    int* bcur      = ib + 300512;        // 64
    int* nbr       = ib + 300576;        // 1600000
    ushort* Whi = (ushort*)(ws + 30800000);
    ushort* Wlo = (ushort*)(ws + 30900000);

    hipMemsetAsync(cnt, 0, (size_t)N_NODES * 4, stream);
    hipMemsetAsync(bcur, 0, 64 * 4, stream);

    prep_weights<<<(W_TOTAL + 255) / 256, 256, 0, stream>>>(w1r, w1l, w2l, w2r, wc1, Whi, Wlo);
    convert_kernel<<<12500, 256, 0, stream>>>(x, xb);

    bucket_kernel<<<NBLK_BKT, 256, 0, stream>>>(srcp, dstp, cnt, bcur, bkt);
    scan_block_sums<<<NBLK_SCAN, 256, 0, stream>>>(cnt, partial);
    scan_top<<<1, 512, 0, stream>>>(partial);
    scan_final<<<NBLK_SCAN, 256, 0, stream>>>(cnt, partial, row_start, cursor);
    fill_bucketed<<<1024, 256, 0, stream>>>(bkt, bcur, cursor, nbr);

    const int NAB = (N_NODES + 3) / 4;
    const int NB  = (N_NODES + 63) / 64;

    agg_mean64_bf16<<<NAB, 256, 0, stream>>>(row_start, cnt, nbr, xb, mean1b);
    g1g2_kernel<<<NB, 256, 0, stream>>>(x, mean1b, Whi, Wlo, b1l, h1hi, y2b);
    agg_mean64_bf16<<<NAB, 256, 0, stream>>>(row_start, cnt, nbr, y2b, mean2b);
    g3g4_kernel<<<NB, 256, 0, stream>>>(h1hi, mean2b, Whi, Wlo, b2l, bc1, uvb);
    edge_kernel<<<(N_EDGES + 255) / 256, 256, 0, stream>>>(srcp, dstp, uvb, wc2, bc2, out);
}